// Round 1
// baseline (60.217 us; speedup 1.0000x reference)
//
#include <hip/hip_runtime.h>
#include <math.h>

// CKConv via Toeplitz collapse:
//   rel = t[s] - t_eval[e] = (s-e)/512 exactly (dyadic), so the SIREN MLP
//   output depends only on d = s-e; causal mask keeps d in [-511, 0].
//   out[e,g] = sum_{s<=e} ( sum_j Ht[s-e+511, j] * A[s,g,j] + B[s,g] )
//   A[s,g,j] = sum_c W3[g*16+c, j] * x[s,c];  B[s,g] = sum_c b3[g*16+c]*x[s,c]
//
// ws float layout:
//   A  [512][16][32]  @ 0        (262144 floats, 1 MB)
//   Ht [512][32]      @ 262144   (16384 floats, 64 KB)   row i: delta = i-511
//   B  [512][16]      @ 278528   (8192 floats, 32 KB)

#define NH 32
#define OMEGA0 32.5f

__global__ __launch_bounds__(64) void ck_prep(
    const float* __restrict__ x,
    const float* __restrict__ t,
    const float* __restrict__ te,
    const float* __restrict__ v1,
    const float* __restrict__ g1,
    const float* __restrict__ b1,
    const float* __restrict__ v2,
    const float* __restrict__ g2,
    const float* __restrict__ b2,
    const float* __restrict__ W3,
    const float* __restrict__ b3,
    float* __restrict__ ws)
{
    const int bid = blockIdx.x;
    const int tid = threadIdx.x;
    float* A  = ws;
    float* Ht = ws + 512*512;
    float* B  = ws + 512*512 + 512*32;

    if (bid < 512) {
        // ---- A[s][g][j] and B[s][g] for s = bid ----
        const int s = bid;
        float xr[16];
        #pragma unroll
        for (int c = 0; c < 16; ++c) xr[c] = x[s*16 + c];

        #pragma unroll
        for (int it = 0; it < 8; ++it) {
            const int p = tid + it*64;          // p = g*32 + j
            const int g = p >> 5;
            const int j = p & 31;
            float acc = 0.f;
            #pragma unroll
            for (int c = 0; c < 16; ++c)
                acc = fmaf(W3[(g*16 + c)*32 + j], xr[c], acc);
            A[s*512 + p] = acc;
        }
        if (tid < 16) {
            float acc = 0.f;
            #pragma unroll
            for (int c = 0; c < 16; ++c)
                acc = fmaf(b3[tid*16 + c], xr[c], acc);
            B[s*16 + tid] = acc;
        }
    } else {
        // ---- Ht rows i = (bid-512)*2 + {0,1};  delta = i-511 in [-511,0] ----
        __shared__ float h1s[2][NH];
        const int sub = tid >> 5;
        const int j   = tid & 31;
        const int i   = (bid - 512)*2 + sub;
        // rel for delta = i-511: pick pair (s=0, e=511-i) from the real inputs
        const float rel = t[0] - te[511 - i];
        // weight-norm layer 1: row norm of (32,1) v1 is |v1[j]|
        const float w1 = g1[j] * v1[j] / fabsf(v1[j]);
        h1s[sub][j] = sinf(OMEGA0 * (rel * w1 + b1[j]));
        __syncthreads();
        float nrm = 0.f, pre = 0.f;
        #pragma unroll
        for (int k = 0; k < NH; ++k) {
            const float w = v2[j*NH + k];
            nrm = fmaf(w, w, nrm);
            pre = fmaf(w, h1s[sub][k], pre);
        }
        const float scale = g2[j] / sqrtf(nrm);
        Ht[i*NH + j] = sinf(OMEGA0 * (scale * pre + b2[j]));
    }
}

__global__ __launch_bounds__(128) void ck_main(const float* __restrict__ ws,
                                               float* __restrict__ out)
{
    const float* A  = ws;
    const float* Ht = ws + 512*512;
    const float* B  = ws + 512*512 + 512*32;

    // load-balance: pair e with 511-e so adjacent blocks sum to ~constant work
    const int bid = blockIdx.x;
    const int e = (bid & 1) ? (511 - (bid >> 1)) : (bid >> 1);

    const int tid = threadIdx.x;
    const int g = tid >> 3;        // 16 output channels
    const int l = tid & 7;         // 8 lanes/channel, each owns j = 4l..4l+3

    const float4* Af = reinterpret_cast<const float4*>(A) + (g*8 + l);
    const float4* Hf = reinterpret_cast<const float4*>(Ht) + l;
    const int i0 = 511 - e;        // Ht row for s = 0

    float4 acc = make_float4(0.f, 0.f, 0.f, 0.f);
    #pragma unroll 4
    for (int s = 0; s <= e; ++s) {
        const float4 a = Af[s*128];          // A[s][g][4l..4l+3], wave-contiguous
        const float4 h = Hf[(i0 + s)*8];     // Ht[i0+s][4l..4l+3], broadcast over g
        acc.x = fmaf(a.x, h.x, acc.x);
        acc.y = fmaf(a.y, h.y, acc.y);
        acc.z = fmaf(a.z, h.z, acc.z);
        acc.w = fmaf(a.w, h.w, acc.w);
    }
    float tot = (acc.x + acc.y) + (acc.z + acc.w);

    // bias-path prefix: sum_{s<=e} B[s,g], strided across the 8 lanes
    float bacc = 0.f;
    for (int s = l; s <= e; s += 8) bacc += B[s*16 + g];
    tot += bacc;

    // reduce the 8 lanes of this g-group (contiguous lanes within a wave)
    tot += __shfl_xor(tot, 1);
    tot += __shfl_xor(tot, 2);
    tot += __shfl_xor(tot, 4);
    if (l == 0) out[e*16 + g] = tot;
}

extern "C" void kernel_launch(void* const* d_in, const int* in_sizes, int n_in,
                              void* d_out, int out_size, void* d_ws, size_t ws_size,
                              hipStream_t stream)
{
    const float* x  = (const float*)d_in[0];
    const float* t  = (const float*)d_in[1];
    const float* te = (const float*)d_in[2];
    const float* v1 = (const float*)d_in[3];
    const float* g1 = (const float*)d_in[4];
    const float* b1 = (const float*)d_in[5];
    const float* v2 = (const float*)d_in[6];
    const float* g2 = (const float*)d_in[7];
    const float* b2 = (const float*)d_in[8];
    const float* W3 = (const float*)d_in[9];
    const float* b3 = (const float*)d_in[10];
    float* out = (float*)d_out;
    float* ws  = (float*)d_ws;

    // prep: blocks [0,512) build A,B; blocks [512,768) build Ht (2 rows each)
    hipLaunchKernelGGL(ck_prep, dim3(768), dim3(64), 0, stream,
                       x, t, te, v1, g1, b1, v2, g2, b2, W3, b3, ws);
    // main: one block per eval position e
    hipLaunchKernelGGL(ck_main, dim3(512), dim3(128), 0, stream, ws, out);
}

// Round 2
// 28.026 us; speedup vs baseline: 2.1486x; 2.1486x over previous
//
#include <hip/hip_runtime.h>
#include <math.h>

// CKConv via Toeplitz collapse + e-tiled sliding-window accumulation.
//
//   rel = t[s] - t_eval[e] = (s-e)/512 exactly, so the SIREN MLP output
//   depends only on d = s-e; causal mask keeps d in [-511, 0].
//   out[e,g] = sum_{s<=e} ( sum_j Ht[511-e+s, j] * A[s,g,j] + B[s,g] )
//   A[s,g,j] = sum_c W3[g*16+c, j] * x[s,c];  B[s,g] = sum_c b3[g*16+c]*x[s,c]
//
// Main kernel: block = (e-tile of 8) x (s-chunk of 32). The 8 Ht rows needed
// at a given s are consecutive (Toeplitz shift), so a ring buffer of 8 float4
// registers slides by one row per s-step: 1 A-load + 1 Ht-load + 32 FMAs.
// Causal mask is free via 8 zero-padded Ht rows (row > 511 => s > e => 0).
// Partials combined with fp32 atomicAdd onto memset-zeroed out.
//
// ws float layout:
//   A   [512][16][32] @ 0        (262144 floats)
//   HtP [520][32]     @ 262144   (rows 512..519 are zeros)
//   B   [512][16]     @ 278784

#define NH 32
#define OMEGA0 32.5f
#define ET 8
#define SC 32

__global__ __launch_bounds__(64) void ck_prep(
    const float* __restrict__ x,
    const float* __restrict__ t,
    const float* __restrict__ te,
    const float* __restrict__ v1,
    const float* __restrict__ g1,
    const float* __restrict__ b1,
    const float* __restrict__ v2,
    const float* __restrict__ g2,
    const float* __restrict__ b2,
    const float* __restrict__ W3,
    const float* __restrict__ b3,
    float* __restrict__ ws)
{
    const int bid = blockIdx.x;
    const int tid = threadIdx.x;
    float* A  = ws;
    float* Ht = ws + 512*512;
    float* B  = ws + 512*512 + 520*32;

    if (bid < 512) {
        // ---- A[s][g][j] and B[s][g] for s = bid ----
        const int s = bid;
        float xr[16];
        #pragma unroll
        for (int c = 0; c < 16; ++c) xr[c] = x[s*16 + c];

        #pragma unroll
        for (int it = 0; it < 8; ++it) {
            const int p = tid + it*64;          // p = g*32 + j
            const int g = p >> 5;
            const int j = p & 31;
            float acc = 0.f;
            #pragma unroll
            for (int c = 0; c < 16; ++c)
                acc = fmaf(W3[(g*16 + c)*32 + j], xr[c], acc);
            A[s*512 + p] = acc;
        }
        if (tid < 16) {
            float acc = 0.f;
            #pragma unroll
            for (int c = 0; c < 16; ++c)
                acc = fmaf(b3[tid*16 + c], xr[c], acc);
            B[s*16 + tid] = acc;
        }
    } else if (bid < 768) {
        // ---- Ht rows i = (bid-512)*2 + {0,1};  delta = i-511 in [-511,0] ----
        __shared__ float h1s[2][NH];
        const int sub = tid >> 5;
        const int j   = tid & 31;
        const int i   = (bid - 512)*2 + sub;
        const float rel = t[0] - te[511 - i];   // == (i-511)/512
        const float w1 = g1[j] * v1[j] / fabsf(v1[j]);
        h1s[sub][j] = sinf(OMEGA0 * (rel * w1 + b1[j]));
        __syncthreads();
        float nrm = 0.f, pre = 0.f;
        #pragma unroll
        for (int k = 0; k < NH; ++k) {
            const float w = v2[j*NH + k];
            nrm = fmaf(w, w, nrm);
            pre = fmaf(w, h1s[sub][k], pre);
        }
        const float scale = g2[j] / sqrtf(nrm);
        Ht[i*NH + j] = sinf(OMEGA0 * (scale * pre + b2[j]));
    } else {
        // ---- zero pad rows 512..519 (the free causal mask) ----
        #pragma unroll
        for (int q = 0; q < 4; ++q)
            Ht[512*NH + tid*4 + q] = 0.f;
    }
}

__global__ __launch_bounds__(128) void ck_main(const float* __restrict__ ws,
                                               float* __restrict__ out)
{
    const int et = blockIdx.y;          // e-tile: e in [8et, 8et+8)
    const int sc = blockIdx.x;          // s-chunk
    const int e0 = et * ET;
    const int s0 = sc * SC;
    const int sEnd = min(s0 + SC, e0 + ET);   // trip count is a multiple of 8
    if (s0 >= sEnd) return;

    const int tid = threadIdx.x;
    const int g = tid >> 3;             // 16 output channels
    const int l = tid & 7;              // j-quad: j = 4l..4l+3

    const float4* A4 = reinterpret_cast<const float4*>(ws);
    const float4* H4 = reinterpret_cast<const float4*>(ws + 512*512);
    const float*  B  = ws + 512*512 + 520*32;

    const int ib = 504 - e0;            // window base: row(e0+k, s) = ib+s+(7-k)

    // ring buffer: r[(s+m)&7] == HtP[ib+s+m] quad l  (invariant at group start)
    float4 r[8];
    #pragma unroll
    for (int m = 0; m < 8; ++m)
        r[m] = H4[(ib + s0 + m)*8 + l];

    float4 acc[8];
    #pragma unroll
    for (int k = 0; k < 8; ++k) acc[k] = make_float4(0.f, 0.f, 0.f, 0.f);

    const int aoff = g*8 + l;
    for (int s = s0; s < sEnd; s += 8) {
        #pragma unroll
        for (int j = 0; j < 8; ++j) {
            const float4 a = A4[(s + j)*128 + aoff];
            #pragma unroll
            for (int k = 0; k < 8; ++k) {
                const float4 h = r[(j + 7 - k) & 7];   // static index
                acc[k].x = fmaf(a.x, h.x, acc[k].x);
                acc[k].y = fmaf(a.y, h.y, acc[k].y);
                acc[k].z = fmaf(a.z, h.z, acc[k].z);
                acc[k].w = fmaf(a.w, h.w, acc[k].w);
            }
            r[j] = H4[(ib + s + j + 8)*8 + l];  // slide window (used next group)
        }
    }

    // reduce each acc[k] over the 8 j-quad lanes; butterfly leaves sum in ALL lanes
    float tot[8];
    #pragma unroll
    for (int k = 0; k < 8; ++k) {
        float v = (acc[k].x + acc[k].y) + (acc[k].z + acc[k].w);
        v += __shfl_xor(v, 1);
        v += __shfl_xor(v, 2);
        v += __shfl_xor(v, 4);
        tot[k] = v;
    }
    // this thread commits k == l (static-index select, no scratch)
    float mytot = 0.f;
    #pragma unroll
    for (int k = 0; k < 8; ++k) mytot = (l == k) ? tot[k] : mytot;

    // bias-prefix term for e = e0 + l over this chunk's s-range
    const int e = e0 + l;
    float bsum = 0.f;
    for (int s = s0; s < sEnd; ++s)
        bsum += (s <= e) ? B[s*16 + g] : 0.f;

    atomicAdd(&out[e*16 + g], mytot + bsum);
}

extern "C" void kernel_launch(void* const* d_in, const int* in_sizes, int n_in,
                              void* d_out, int out_size, void* d_ws, size_t ws_size,
                              hipStream_t stream)
{
    const float* x  = (const float*)d_in[0];
    const float* t  = (const float*)d_in[1];
    const float* te = (const float*)d_in[2];
    const float* v1 = (const float*)d_in[3];
    const float* g1 = (const float*)d_in[4];
    const float* b1 = (const float*)d_in[5];
    const float* v2 = (const float*)d_in[6];
    const float* g2 = (const float*)d_in[7];
    const float* b2 = (const float*)d_in[8];
    const float* W3 = (const float*)d_in[9];
    const float* b3 = (const float*)d_in[10];
    float* out = (float*)d_out;
    float* ws  = (float*)d_ws;

    // out accumulates via atomics -> zero it first (also clears 0xAA poison)
    hipMemsetAsync(out, 0, (size_t)out_size * sizeof(float), stream);

    // prep: [0,512) -> A,B ; [512,768) -> Ht ; 768 -> zero pad rows
    hipLaunchKernelGGL(ck_prep, dim3(769), dim3(64), 0, stream,
                       x, t, te, v1, g1, b1, v2, g2, b2, W3, b3, ws);

    // main: grid (s-chunk, e-tile); inactive chunks exit immediately
    hipLaunchKernelGGL(ck_main, dim3(16, 64), dim3(128), 0, stream, ws, out);
}

// Round 3
// 20.056 us; speedup vs baseline: 3.0024x; 1.3974x over previous
//
#include <hip/hip_runtime.h>
#include <math.h>

// CKConv via Toeplitz collapse + e-tiled sliding-window accumulation.
//
//   rel = t[s] - t_eval[e] = (s-e)/512 exactly, so the SIREN MLP output
//   depends only on d = s-e; causal mask keeps d in [-511, 0].
//   out[e,g] = sum_{s<=e} ( sum_j Ht[511-e+s, j] * A[s,g,j] + B[s,g] )
//   A[s,g,j] = sum_c W3[g*16+c, j] * x[s,c];  B[s,g] = sum_c b3[g*16+c]*x[s,c]
//
// Main kernel: block = (e-tile of 8) x (s-chunk of 32), uniform 32 s-steps.
// The 8 Ht rows needed at a given s are consecutive (Toeplitz shift), so a
// ring of 8 float4 registers slides one row per s-step. A-loads are double-
// buffered (aC/aN) so each group's 8 loads are issued a full 256-FMA group
// (~512 cyc) before use -> L2/L3 latency hidden at 1 wave/SIMD.
// Causal mask is free via zero-padded Ht rows 512..543 (row>511 => s>e => 0).
// out is zeroed by ck_prep; partials combined with fp32 atomicAdd.
//
// ws float layout:
//   A   [512][16][32] @ 0        (262144 floats)
//   HtP [544][32]     @ 262144   (rows 512..543 zero)
//   B   [512][16]     @ 279552

#define NH 32
#define OMEGA0 32.5f
#define ET 8
#define SC 32

__global__ __launch_bounds__(64) void ck_prep(
    const float* __restrict__ x,
    const float* __restrict__ t,
    const float* __restrict__ te,
    const float* __restrict__ v1,
    const float* __restrict__ g1,
    const float* __restrict__ b1,
    const float* __restrict__ v2,
    const float* __restrict__ g2,
    const float* __restrict__ b2,
    const float* __restrict__ W3,
    const float* __restrict__ b3,
    float* __restrict__ ws,
    float* __restrict__ out)
{
    const int bid = blockIdx.x;
    const int tid = threadIdx.x;
    float* A  = ws;
    float* Ht = ws + 512*512;
    float* B  = ws + 512*512 + 544*32;

    if (bid < 512) {
        // ---- A[s][g][j] and B[s][g] for s = bid; also zero out[s] ----
        const int s = bid;
        float xr[16];
        #pragma unroll
        for (int c = 0; c < 16; ++c) xr[c] = x[s*16 + c];

        #pragma unroll
        for (int it = 0; it < 8; ++it) {
            const int p = tid + it*64;          // p = g*32 + j
            const int g = p >> 5;
            const int j = p & 31;
            float acc = 0.f;
            #pragma unroll
            for (int c = 0; c < 16; ++c)
                acc = fmaf(W3[(g*16 + c)*32 + j], xr[c], acc);
            A[s*512 + p] = acc;
        }
        if (tid < 16) {
            float acc = 0.f;
            #pragma unroll
            for (int c = 0; c < 16; ++c)
                acc = fmaf(b3[tid*16 + c], xr[c], acc);
            B[s*16 + tid] = acc;
            out[s*16 + tid] = 0.f;              // replaces memset dispatch
        }
    } else if (bid < 768) {
        // ---- Ht rows i = (bid-512)*2 + {0,1};  delta = i-511 in [-511,0] ----
        __shared__ float h1s[2][NH];
        const int sub = tid >> 5;
        const int j   = tid & 31;
        const int i   = (bid - 512)*2 + sub;
        const float rel = t[0] - te[511 - i];   // == (i-511)/512
        const float w1 = g1[j] * v1[j] / fabsf(v1[j]);
        h1s[sub][j] = sinf(OMEGA0 * (rel * w1 + b1[j]));
        __syncthreads();
        float nrm = 0.f, pre = 0.f;
        #pragma unroll
        for (int k = 0; k < NH; ++k) {
            const float w = v2[j*NH + k];
            nrm = fmaf(w, w, nrm);
            pre = fmaf(w, h1s[sub][k], pre);
        }
        const float scale = g2[j] / sqrtf(nrm);
        Ht[i*NH + j] = sinf(OMEGA0 * (scale * pre + b2[j]));
    } else {
        // ---- zero pad rows 512..543 (the free causal mask): 1024 floats ----
        #pragma unroll
        for (int q = 0; q < 16; ++q)
            Ht[512*NH + tid + q*64] = 0.f;
    }
}

__global__ __launch_bounds__(128) void ck_main(const float* __restrict__ ws,
                                               float* __restrict__ out)
{
    const int et = blockIdx.y;          // e-tile: e in [8et, 8et+8)
    const int sc = blockIdx.x;          // s-chunk: s in [32sc, 32sc+32)
    const int e0 = et * ET;
    const int s0 = sc * SC;
    if (s0 >= e0 + ET) return;          // fully masked chunk

    const int tid = threadIdx.x;
    const int g = tid >> 3;             // 16 output channels
    const int l = tid & 7;              // j-quad: j = 4l..4l+3

    const float4* A4 = reinterpret_cast<const float4*>(ws);
    const float4* H4 = reinterpret_cast<const float4*>(ws + 512*512);
    const float*  B  = ws + 512*512 + 544*32;

    const int ib = 504 - e0;            // window base: row(e0+k, s) = ib+s+(7-k)
    const float4* Ap = A4 + (g*8 + l);

    // ring: r[(s+m)&7] == HtP[ib+s+m] quad l   ((s0 % 8) == 0)
    float4 r[8];
    #pragma unroll
    for (int m = 0; m < 8; ++m)
        r[m] = H4[(ib + s0 + m)*8 + l];

    // A double-buffer: current and next group of 8 rows
    float4 aC[8], aN[8];
    #pragma unroll
    for (int j = 0; j < 8; ++j) aC[j] = Ap[(s0 + j)*128];

    float4 acc[8];
    #pragma unroll
    for (int k = 0; k < 8; ++k) acc[k] = make_float4(0.f, 0.f, 0.f, 0.f);

    #pragma unroll
    for (int grp = 0; grp < 4; ++grp) {
        const int s = s0 + grp*8;
        // issue next group's A-loads BEFORE this group's 256 FMAs
        if (grp < 3) {
            #pragma unroll
            for (int j = 0; j < 8; ++j) aN[j] = Ap[(s + 8 + j)*128];
        }
        #pragma unroll
        for (int j = 0; j < 8; ++j) {
            const float4 a = aC[j];
            #pragma unroll
            for (int k = 0; k < 8; ++k) {
                const float4 h = r[(j + 7 - k) & 7];   // static ring index
                acc[k].x = fmaf(a.x, h.x, acc[k].x);
                acc[k].y = fmaf(a.y, h.y, acc[k].y);
                acc[k].z = fmaf(a.z, h.z, acc[k].z);
                acc[k].w = fmaf(a.w, h.w, acc[k].w);
            }
            r[j] = H4[(ib + s + j + 8)*8 + l];  // slide window (next group's rows)
        }
        if (grp < 3) {
            #pragma unroll
            for (int j = 0; j < 8; ++j) aC[j] = aN[j];
        }
    }

    // reduce each acc[k] over the 8 j-quad lanes (butterfly -> all lanes)
    float tot[8];
    #pragma unroll
    for (int k = 0; k < 8; ++k) {
        float v = (acc[k].x + acc[k].y) + (acc[k].z + acc[k].w);
        v += __shfl_xor(v, 1);
        v += __shfl_xor(v, 2);
        v += __shfl_xor(v, 4);
        tot[k] = v;
    }
    // thread (g,l) commits e = e0 + l  (static-index select, no scratch)
    float mytot = 0.f;
    #pragma unroll
    for (int k = 0; k < 8; ++k) mytot = (l == k) ? tot[k] : mytot;

    // bias-prefix term for e = e0 + l over this chunk's s-range
    const int e = e0 + l;
    float bsum = 0.f;
    #pragma unroll
    for (int q = 0; q < SC; ++q) {
        const int s = s0 + q;
        bsum += (s <= e) ? B[s*16 + g] : 0.f;
    }

    atomicAdd(&out[e*16 + g], mytot + bsum);
}

extern "C" void kernel_launch(void* const* d_in, const int* in_sizes, int n_in,
                              void* d_out, int out_size, void* d_ws, size_t ws_size,
                              hipStream_t stream)
{
    const float* x  = (const float*)d_in[0];
    const float* t  = (const float*)d_in[1];
    const float* te = (const float*)d_in[2];
    const float* v1 = (const float*)d_in[3];
    const float* g1 = (const float*)d_in[4];
    const float* b1 = (const float*)d_in[5];
    const float* v2 = (const float*)d_in[6];
    const float* g2 = (const float*)d_in[7];
    const float* b2 = (const float*)d_in[8];
    const float* W3 = (const float*)d_in[9];
    const float* b3 = (const float*)d_in[10];
    float* out = (float*)d_out;
    float* ws  = (float*)d_ws;

    // prep: [0,512) -> A,B + zero out ; [512,768) -> Ht ; 768 -> zero pad rows
    hipLaunchKernelGGL(ck_prep, dim3(769), dim3(64), 0, stream,
                       x, t, te, v1, g1, b1, v2, g2, b2, W3, b3, ws, out);

    // main: grid (s-chunk, e-tile); inactive chunks exit immediately
    hipLaunchKernelGGL(ck_main, dim3(16, 64), dim3(128), 0, stream, ws, out);
}